// Round 8
// baseline (48.502 us; speedup 1.0000x reference)
//
#include <hip/hip_runtime.h>
#include <hip/hip_bf16.h>

typedef __attribute__((ext_vector_type(8))) short short8;
typedef __attribute__((ext_vector_type(4))) float f32x4;

#define OUT_DIM 11008
#define IN_DIM  4096
#define B_DIM   32
#define KSPL    8
#define KPB     (IN_DIM / KSPL)        // 512 k per block
#define PART_ELEMS (B_DIM * OUT_DIM)   // 352256 floats per partial

__device__ __forceinline__ short8 cvt8(const float* __restrict__ src) {
  f32x4 f0 = *reinterpret_cast<const f32x4*>(src);
  f32x4 f1 = *reinterpret_cast<const f32x4*>(src + 4);
  short8 v;
  __hip_bfloat16 h;
  h = __float2bfloat16(f0[0]); v[0] = *reinterpret_cast<short*>(&h);
  h = __float2bfloat16(f0[1]); v[1] = *reinterpret_cast<short*>(&h);
  h = __float2bfloat16(f0[2]); v[2] = *reinterpret_cast<short*>(&h);
  h = __float2bfloat16(f0[3]); v[3] = *reinterpret_cast<short*>(&h);
  h = __float2bfloat16(f1[0]); v[4] = *reinterpret_cast<short*>(&h);
  h = __float2bfloat16(f1[1]); v[5] = *reinterpret_cast<short*>(&h);
  h = __float2bfloat16(f1[2]); v[6] = *reinterpret_cast<short*>(&h);
  h = __float2bfloat16(f1[3]); v[7] = *reinterpret_cast<short*>(&h);
  return v;
}

// R7 economics (42.0us) + in-block 2-way k-combine: block = 128 cols x 512 k,
// waves = 2 col-groups x 2 k-halves. Halves split-K partial traffic (8 vs 16
// partials). LDS x-buffer (32KB) is re-used for the combine after a barrier.
__global__ __launch_bounds__(256, 4)
void bitnet_partial(const float* __restrict__ x,
                    const float* __restrict__ w,
                    float* __restrict__ ws)
{
  __shared__ __align__(16) char smem[32768];
  short* xl  = (short*)smem;   // xl[(t*2+m)*512 + lane*8], t=0..15 (512 k)
  float* red = (float*)smem;   // after k-loop: red[ng*2048 + j*64 + lane]

  const int tid  = threadIdx.x;
  const int lane = tid & 63;
  const int wv   = tid >> 6;
  const int ng   = wv & 1;         // col group (0: cols 0-63, 1: 64-127)
  const int kh   = wv >> 1;        // k-half of the block's 512 k
  const int l15  = lane & 15;
  const int lg   = lane >> 4;
  const int ow    = blockIdx.x * 128 + ng * 64;
  const int kbase = blockIdx.y * KPB;
  const int k0    = kbase + kh * 256;

  // ---- stage x once: 32 rows x 512 k as bf16 A-fragments (2048 octets) ----
#pragma unroll
  for (int i = 0; i < 8; ++i) {
    const int o   = i * 256 + tid;
    const int t   = o >> 7;
    const int m   = (o >> 6) & 1;
    const int ln  = o & 63;
    const int row = m * 16 + (ln & 15);
    const int kof = t * 32 + (ln >> 4) * 8;
    short8 v = cvt8(x + (size_t)row * IN_DIM + kbase + kof);
    *reinterpret_cast<short8*>(&xl[(size_t)(t * 2 + m) * 512 + ln * 8]) = v;
  }
  __syncthreads();

  f32x4 acc[2][4];
#pragma unroll
  for (int m = 0; m < 2; ++m)
#pragma unroll
    for (int n = 0; n < 4; ++n)
      acc[m][n] = (f32x4){0.f, 0.f, 0.f, 0.f};

  const float* wbase = w + (size_t)(ow + l15) * IN_DIM + k0 + lg * 8;

#pragma unroll 2
  for (int t = 0; t < 8; ++t) {    // 8 k-steps of 32 per wave
    const int kk = t * 32;
    short8 aa[2], bb[4];
    aa[0] = *reinterpret_cast<const short8*>(&xl[(size_t)((kh * 8 + t) * 2 + 0) * 512 + lane * 8]);
    aa[1] = *reinterpret_cast<const short8*>(&xl[(size_t)((kh * 8 + t) * 2 + 1) * 512 + lane * 8]);
#pragma unroll
    for (int n = 0; n < 4; ++n)
      bb[n] = cvt8(wbase + (size_t)n * 16 * IN_DIM + kk);
#pragma unroll
    for (int m = 0; m < 2; ++m)
#pragma unroll
      for (int n = 0; n < 4; ++n)
        acc[m][n] = __builtin_amdgcn_mfma_f32_16x16x32_bf16(aa[m], bb[n], acc[m][n], 0, 0, 0);
  }
  __syncthreads();   // xl reads done; safe to overwrite as red

  // ---- k-half combine: kh=1 publishes, kh=0 adds and stores the partial ----
  if (kh == 1) {
#pragma unroll
    for (int m = 0; m < 2; ++m)
#pragma unroll
      for (int n = 0; n < 4; ++n)
#pragma unroll
        for (int r = 0; r < 4; ++r)
          red[ng * 2048 + ((m * 4 + n) * 4 + r) * 64 + lane] = acc[m][n][r];
  }
  __syncthreads();
  if (kh == 0) {
    float* out = ws + (size_t)blockIdx.y * PART_ELEMS;
#pragma unroll
    for (int m = 0; m < 2; ++m)
#pragma unroll
      for (int n = 0; n < 4; ++n)
#pragma unroll
        for (int r = 0; r < 4; ++r) {
          const float v = acc[m][n][r] + red[ng * 2048 + ((m * 4 + n) * 4 + r) * 64 + lane];
          const int brow = m * 16 + lg * 4 + r;   // C/D: row=(lane>>4)*4+reg
          const int o    = ow + n * 16 + l15;     // col=lane&15
          out[(size_t)brow * OUT_DIM + o] = v;
        }
  }
}

// y[b][o] = scale * sum_{s<8} ws[s][b][o]
__global__ __launch_bounds__(256)
void bitnet_reduce(const float* __restrict__ ws,
                   const float* __restrict__ scale,
                   float* __restrict__ y)
{
  const size_t base = ((size_t)blockIdx.x * 256 + threadIdx.x) * 4;
  f32x4 s = (f32x4){0.f, 0.f, 0.f, 0.f};
#pragma unroll
  for (int i = 0; i < KSPL; ++i) {
    f32x4 v = *reinterpret_cast<const f32x4*>(ws + (size_t)i * PART_ELEMS + base);
    s += v;
  }
  const float sc = scale[0];
  s *= sc;
  *reinterpret_cast<f32x4*>(y + base) = s;
}

extern "C" void kernel_launch(void* const* d_in, const int* in_sizes, int n_in,
                              void* d_out, int out_size, void* d_ws, size_t ws_size,
                              hipStream_t stream) {
  const float* x = (const float*)d_in[0];
  const float* w = (const float*)d_in[1];
  const float* s = (const float*)d_in[2];
  float* y  = (float*)d_out;
  float* ws = (float*)d_ws;   // KSPL*PART_ELEMS*4 = 11.27 MB

  dim3 grid(OUT_DIM / 128, KSPL);   // 86 x 8 = 688 blocks, fully resident
  bitnet_partial<<<grid, 256, 0, stream>>>(x, w, ws);
  bitnet_reduce<<<PART_ELEMS / 1024, 256, 0, stream>>>(ws, s, y);
}

// Round 9
// 39.852 us; speedup vs baseline: 1.2170x; 1.2170x over previous
//
#include <hip/hip_runtime.h>
#include <hip/hip_bf16.h>

typedef __attribute__((ext_vector_type(8))) short short8;
typedef __attribute__((ext_vector_type(4))) float f32x4;

#define OUT_DIM 11008
#define IN_DIM  4096
#define B_DIM   32
#define KSPL    16
#define KPB     (IN_DIM / KSPL)        // 256 k per split-K block
#define PART_ELEMS (B_DIM * OUT_DIM)   // 352256 elems per partial slice

__device__ __forceinline__ short8 cvt8(const float* __restrict__ src) {
  f32x4 f0 = *reinterpret_cast<const f32x4*>(src);
  f32x4 f1 = *reinterpret_cast<const f32x4*>(src + 4);
  short8 v;
  __hip_bfloat16 h;
  h = __float2bfloat16(f0[0]); v[0] = *reinterpret_cast<short*>(&h);
  h = __float2bfloat16(f0[1]); v[1] = *reinterpret_cast<short*>(&h);
  h = __float2bfloat16(f0[2]); v[2] = *reinterpret_cast<short*>(&h);
  h = __float2bfloat16(f0[3]); v[3] = *reinterpret_cast<short*>(&h);
  h = __float2bfloat16(f1[0]); v[4] = *reinterpret_cast<short*>(&h);
  h = __float2bfloat16(f1[1]); v[5] = *reinterpret_cast<short*>(&h);
  h = __float2bfloat16(f1[2]); v[6] = *reinterpret_cast<short*>(&h);
  h = __float2bfloat16(f1[3]); v[7] = *reinterpret_cast<short*>(&h);
  return v;
}

// R7 structure exactly (42.0us best), ONE change: split-K partials stored as
// bf16 (halves ws write + reduce read traffic). K-loop/staging untouched.
__global__ __launch_bounds__(256, 4)
void bitnet_partial(const float* __restrict__ x,
                    const float* __restrict__ w,
                    unsigned short* __restrict__ ws)
{
  __shared__ short xl[8][2][64 * 8];   // 16 KB: bf16 A-fragments, staged once

  const int tid  = threadIdx.x;
  const int lane = tid & 63;
  const int wv   = tid >> 6;       // wave 0..3
  const int l15  = lane & 15;
  const int lg   = lane >> 4;      // 0..3
  const int ow   = blockIdx.x * 256 + wv * 64;   // wave's output-col base
  const int k0   = blockIdx.y * KPB;

  // ---- stage x fragments once: 1024 octets, 256 threads x 4 ----
#pragma unroll
  for (int i = 0; i < 4; ++i) {
    const int o   = i * 256 + tid;
    const int t   = o >> 7;
    const int m   = (o >> 6) & 1;
    const int ln  = o & 63;
    const int row = m * 16 + (ln & 15);
    const int kof = t * 32 + (ln >> 4) * 8;
    short8 v = cvt8(x + (size_t)row * IN_DIM + k0 + kof);
    *reinterpret_cast<short8*>(&xl[t][m][ln * 8]) = v;
  }
  __syncthreads();

  f32x4 acc[2][4];
#pragma unroll
  for (int m = 0; m < 2; ++m)
#pragma unroll
    for (int n = 0; n < 4; ++n)
      acc[m][n] = (f32x4){0.f, 0.f, 0.f, 0.f};

  const float* wbase = w + (size_t)(ow + l15) * IN_DIM + k0 + lg * 8;

#pragma unroll 2
  for (int t = 0; t < KPB / 32; ++t) {
    const int kk = t * 32;
    short8 aa[2], bb[4];
    aa[0] = *reinterpret_cast<const short8*>(&xl[t][0][lane * 8]);
    aa[1] = *reinterpret_cast<const short8*>(&xl[t][1][lane * 8]);
#pragma unroll
    for (int n = 0; n < 4; ++n)
      bb[n] = cvt8(wbase + (size_t)n * 16 * IN_DIM + kk);
#pragma unroll
    for (int m = 0; m < 2; ++m)
#pragma unroll
      for (int n = 0; n < 4; ++n)
        acc[m][n] = __builtin_amdgcn_mfma_f32_16x16x32_bf16(aa[m], bb[n], acc[m][n], 0, 0, 0);
  }

  // partial store (bf16): ws[blockIdx.y][b][o]
  unsigned short* out = ws + (size_t)blockIdx.y * PART_ELEMS;
#pragma unroll
  for (int m = 0; m < 2; ++m)
#pragma unroll
    for (int n = 0; n < 4; ++n)
#pragma unroll
      for (int r = 0; r < 4; ++r) {
        const int brow = m * 16 + lg * 4 + r;   // C/D: row = (lane>>4)*4 + reg
        const int o    = ow + n * 16 + l15;     // col = lane&15
        __hip_bfloat16 h = __float2bfloat16(acc[m][n][r]);
        out[(size_t)brow * OUT_DIM + o] = *reinterpret_cast<unsigned short*>(&h);
      }
}

// y[b][o] = scale * sum_{s<16} bf16 ws[s][b][o]; 8 outputs/thread, short8 loads
__global__ __launch_bounds__(256)
void bitnet_reduce(const unsigned short* __restrict__ ws,
                   const float* __restrict__ scale,
                   float* __restrict__ y)
{
  const size_t base = ((size_t)blockIdx.x * 256 + threadIdx.x) * 8;
  float s[8] = {0.f, 0.f, 0.f, 0.f, 0.f, 0.f, 0.f, 0.f};
#pragma unroll
  for (int i = 0; i < KSPL; ++i) {
    short8 v = *reinterpret_cast<const short8*>(ws + (size_t)i * PART_ELEMS + base);
#pragma unroll
    for (int j = 0; j < 8; ++j) {
      const unsigned int u = ((unsigned int)(unsigned short)v[j]) << 16;
      s[j] += __uint_as_float(u);
    }
  }
  const float sc = scale[0];
  f32x4 o0 = (f32x4){s[0] * sc, s[1] * sc, s[2] * sc, s[3] * sc};
  f32x4 o1 = (f32x4){s[4] * sc, s[5] * sc, s[6] * sc, s[7] * sc};
  *reinterpret_cast<f32x4*>(y + base)     = o0;
  *reinterpret_cast<f32x4*>(y + base + 4) = o1;
}

extern "C" void kernel_launch(void* const* d_in, const int* in_sizes, int n_in,
                              void* d_out, int out_size, void* d_ws, size_t ws_size,
                              hipStream_t stream) {
  const float* x = (const float*)d_in[0];
  const float* w = (const float*)d_in[1];
  const float* s = (const float*)d_in[2];
  float* y = (float*)d_out;
  unsigned short* ws = (unsigned short*)d_ws;   // KSPL*PART_ELEMS*2 = 11.27 MB

  dim3 grid(OUT_DIM / 256, KSPL);   // 43 x 16 = 688 blocks, fully resident
  bitnet_partial<<<grid, 256, 0, stream>>>(x, w, ws);
  bitnet_reduce<<<PART_ELEMS / 2048, 256, 0, stream>>>(ws, s, y);
}